// Round 10
// baseline (230.473 us; speedup 1.0000x reference)
//
#include <hip/hip_runtime.h>
#include <hip/hip_bf16.h>
#include <hip/hip_cooperative_groups.h>
#include <stdint.h>

namespace cg = cooperative_groups;

typedef __attribute__((ext_vector_type(8))) short bf16x8;
typedef __attribute__((ext_vector_type(4))) float f32x4;

#define NP 2048
#define NBANK 65536
#define NCHUNKS 32
#define CHUNK 2048
#define SUBR 64
#define NSUB 32
#define CF 261

__device__ inline short f2bf(float f) {
  __hip_bfloat16 h = __float2bfloat16(f);
  return *reinterpret_cast<short*>(&h);
}

// ============================================================================
// Shared device helpers (used by both fused and fallback paths)
// ============================================================================

// ---- conv(8x8 s8)+relu + antialiased resize + fusion for 8 positions -------
// 256 threads; shmem layout: patch@0(6144) fusedS@6144(8448) gv@14592(640)
// gw@15232(640) redS@15872(128). Needs < 16KB.
__device__ void conv_block_256(
    unsigned char* shmem, int bid, int t,
    const float* __restrict__ image, const float* __restrict__ geometry,
    const float* __restrict__ bw, const float* __restrict__ bb,
    const float* __restrict__ fwp, const float* __restrict__ fb,
    short* __restrict__ flatb, float* __restrict__ qsq, float* __restrict__ wgt)
{
  float* patch = (float*)shmem;
  float (*fusedS)[264] = (float (*)[264])(shmem + 6144);
  float (*gv)[4] = (float (*)[4])(shmem + 14592);
  float (*gw)[4] = (float (*)[4])(shmem + 15232);
  float (*redS)[8] = (float (*)[8])(shmem + 15872);

  int b = bid >> 7, rem = bid & 127, h = rem >> 2, w0 = (rem & 3) * 8;

  #pragma unroll
  for (int j = 0; j < 6; j++) {           // stage 3x8x64 image patch
    int idx = t + j * 256;
    int c = idx >> 9, r = (idx >> 6) & 7, col = idx & 63;
    patch[idx] = image[(((size_t)(b*3 + c) * 256) + 8*h + r) * 256 + 8*w0 + col];
  }
  if (t < 24) {                           // zero pad fused[i][261..263]
    int i = t / 3, c = 261 + t % 3;
    fusedS[i][c] = 0.f;
  }
  if (t < 160) {                          // resize partials: 40 vals x 4 subs
    int v = t >> 2, sub = t & 3;
    int i = v / 5, cg5 = v % 5;
    int jj = w0 + i;
    float val = 0.f, ws = 0.f;
    const float* gch = geometry + (size_t)(b*5 + cg5) * 65536;
    #pragma unroll
    for (int rr = 0; rr < 4; rr++) {
      int r = sub * 4 + rr;
      int gr = 8*h - 4 + r;
      float wr = 1.f - fabsf((float)r - 7.5f) * 0.125f;
      if (gr >= 0 && gr < 256) {
        const float* grow = gch + (size_t)gr * 256;
        for (int c = 0; c < 16; c++) {
          int gc = 8*jj - 4 + c;
          if (gc >= 0 && gc < 256) {
            float wc_ = 1.f - fabsf((float)c - 7.5f) * 0.125f;
            val += wr * wc_ * grow[gc];
            ws  += wr * wc_;
          }
        }
      }
    }
    gv[v][sub] = val; gw[v][sub] = ws;
  }
  __syncthreads();
  if (t < 40) {
    int i = t / 5, cg5 = t % 5;
    float sv = gv[t][0] + gv[t][1] + gv[t][2] + gv[t][3];
    float sw = gw[t][0] + gw[t][1] + gw[t][2] + gw[t][3];
    fusedS[i][256 + cg5] = sv / sw;
  }

  float acc[8];
  #pragma unroll
  for (int i = 0; i < 8; i++) acc[i] = 0.f;
  const float4* wo4 = (const float4*)(bw + (size_t)t * 192);
  for (int cr = 0; cr < 24; cr++) {       // conv, broadcast LDS float4
    const float4* prow4 = (const float4*)&patch[cr * 64];
    float4 wA = wo4[cr*2], wB = wo4[cr*2 + 1];
    #pragma unroll
    for (int i = 0; i < 8; i++) {
      float4 p0 = prow4[i*2], p1 = prow4[i*2 + 1];
      acc[i] += wA.x*p0.x + wA.y*p0.y + wA.z*p0.z + wA.w*p0.w
              + wB.x*p1.x + wB.y*p1.y + wB.z*p1.z + wB.w*p1.w;
    }
  }
  float bias = bb[t];
  #pragma unroll
  for (int i = 0; i < 8; i++) fusedS[i][t] = fmaxf(acc[i] + bias, 0.f);
  __syncthreads();

  #pragma unroll
  for (int i = 0; i < 8; i++) acc[i] = 0.f;
  const float4* fwo4 = (const float4*)(fwp + (size_t)t * 264);
  for (int c4 = 0; c4 < 66; c4++) {       // fusion matmul, broadcast float4
    float4 w4 = fwo4[c4];
    #pragma unroll
    for (int i = 0; i < 8; i++) {
      float4 f4 = *(const float4*)&fusedS[i][c4*4];
      acc[i] += w4.x*f4.x + w4.y*f4.y + w4.z*f4.z + w4.w*f4.w;
    }
  }
  float fbias = fb[t];
  int lane = t & 63, wvid = t >> 6;
  #pragma unroll
  for (int i = 0; i < 8; i++) {
    acc[i] += fbias;
    int p = b*1024 + h*32 + w0 + i;
    flatb[(size_t)p * 256 + t] = f2bf(acc[i]);
    float s = acc[i] * acc[i];
    #pragma unroll
    for (int m = 1; m < 64; m <<= 1) s += __shfl_xor(s, m);
    if (lane == 0) redS[wvid][i] = s;
  }
  __syncthreads();
  if (t < 8) {
    float s = redS[0][t] + redS[1][t] + redS[2][t] + redS[3][t];
    int p = b*1024 + h*32 + w0 + t;
    qsq[p] = s;
    float den = fusedS[t][256+3], opa = fusedS[t][256+2], ani = fusedS[t][256+4];
    float base2 = 0.5f*den + 0.25f*(1.f - opa) + 0.25f*ani;
    wgt[p] = 1.f + 1.f/(1.f + expf(-4.f*(base2 - 0.5f)));
  }
}

// ---- one 64-row bank subtile -> fragment-tiled bf16 (32KB bounce) ----------
// 256 threads. Tiled layout: 16B slot (c,l4,l15) at c*1024+l4*256+l15*16
// holds row (c>>4)*32+((c>>3)&1)*16+l15, k-bytes (c&7)*64+l4*16.
__device__ void bank_subtile_256(
    unsigned char* shmem, int s, int t,
    const float* __restrict__ mb, short* __restrict__ mbb,
    float* __restrict__ msq)
{
  int r = t >> 2, q4 = t & 3;
  int wcs = r >> 5, hh = (r >> 4) & 1, l15r = r & 15;
  const float* src = mb + ((size_t)s * 64 + r) * 256;
  float s2 = 0.f;
  #pragma unroll
  for (int qq = q4; qq < 8; qq += 4) {
    int l4 = (qq >> 1) & 3, b8 = (qq & 1) * 8;
    #pragma unroll
    for (int i = 0; i < 8; i++) {
      float4 v = *(const float4*)(src + qq * 4 + i * 32);
      short4 o; o.x = f2bf(v.x); o.y = f2bf(v.y); o.z = f2bf(v.z); o.w = f2bf(v.w);
      int c = wcs * 16 + hh * 8 + i;
      *(short4*)(shmem + c * 1024 + l4 * 256 + l15r * 16 + b8) = o;
      s2 += v.x*v.x + v.y*v.y + v.z*v.z + v.w*v.w;
    }
  }
  s2 += __shfl_xor(s2, 1); s2 += __shfl_xor(s2, 2);
  if (q4 == 0) msq[(size_t)s * 64 + r] = s2;
  __syncthreads();
  unsigned char* dstg = (unsigned char*)mbb + (size_t)s * 32768;
  #pragma unroll
  for (int i = 0; i < 8; i++) {
    int S = t + i * 256;
    *(float4*)(dstg + S * 16) = *(const float4*)(shmem + S * 16);
  }
  __syncthreads();
}

// ---- distmin body: R8 structure, red overlaid into sB[0] (LDS 64KB) --------
__device__ void distmin_block(
    unsigned char* shmem, int nc, int mt, int t,
    const short* __restrict__ Aq, const short* __restrict__ Bb,
    const float* __restrict__ qsq, const float* __restrict__ msq,
    float* __restrict__ partial)
{
  unsigned char (*sB)[32768] = (unsigned char (*)[32768])shmem;   // 64KB
  float (*red)[128] = (float (*)[128])shmem;  // overlays sB[0][0..1023], dead by then
  int lane = t & 63, wid = t >> 6;
  int wr = wid >> 1, wc = wid & 1;
  const int l15 = lane & 15, l4 = lane >> 4;
  int m0 = mt * 128;
  const size_t nchunk0 = (size_t)nc * CHUNK;
  const unsigned char* Bbyte = (const unsigned char*)Bb + nchunk0 * 512;
  const unsigned char* Abyte = (const unsigned char*)Aq;

  bf16x8 af[4][8];
  #pragma unroll
  for (int mi = 0; mi < 4; mi++)
    #pragma unroll
    for (int ks = 0; ks < 8; ks++)
      af[mi][ks] = *(const bf16x8*)(Abyte +
          (size_t)(m0 + wr*64 + mi*16 + l15) * 512 + ks*64 + l4*16);

  float vmin[4][4];
  #pragma unroll
  for (int mi = 0; mi < 4; mi++)
    #pragma unroll
    for (int r = 0; r < 4; r++) vmin[mi][r] = 3.4e38f;

#define STAGE(bufsel, sidx) do {                                              \
    const unsigned char* gb_ = Bbyte + (size_t)(sidx) * 32768 + wid * 1024 + lane * 16; \
    unsigned char* lb_ = &sB[bufsel][0] + wid * 1024;                         \
    _Pragma("unroll")                                                         \
    for (int j_ = 0; j_ < 8; j_++) {                                          \
      __builtin_amdgcn_global_load_lds(                                       \
        (const __attribute__((address_space(1))) unsigned int*)(gb_ + j_*4096), \
        (__attribute__((address_space(3))) unsigned int*)(lb_ + j_*4096),     \
        16, 0, 0);                                                            \
    }                                                                         \
  } while (0)

  STAGE(0, 0);
  __syncthreads();

  int cur = 0;
  for (int s = 0; s < NSUB; s++) {
    if (s + 1 < NSUB) STAGE(cur ^ 1, s + 1);
    const size_t nb = nchunk0 + (size_t)s * SUBR;
    float msq0 = msq[nb + wc * 32 + l15];
    float msq1 = msq[nb + wc * 32 + 16 + l15];
    const unsigned char* buf = &sB[cur][0] + wc * 16384;

    f32x4 acc[4][2];
    #pragma unroll
    for (int mi = 0; mi < 4; mi++) {
      acc[mi][0] = (f32x4){0.f, 0.f, 0.f, 0.f};
      acc[mi][1] = (f32x4){0.f, 0.f, 0.f, 0.f};
    }
    #pragma unroll
    for (int ks = 0; ks < 8; ks++) {
      bf16x8 b0 = *(const bf16x8*)(buf + ks*1024 + l4*256 + l15*16);
      bf16x8 b1 = *(const bf16x8*)(buf + 8192 + ks*1024 + l4*256 + l15*16);
      #pragma unroll
      for (int mi = 0; mi < 4; mi++) {
        acc[mi][0] = __builtin_amdgcn_mfma_f32_16x16x32_bf16(af[mi][ks], b0, acc[mi][0], 0, 0, 0);
        acc[mi][1] = __builtin_amdgcn_mfma_f32_16x16x32_bf16(af[mi][ks], b1, acc[mi][1], 0, 0, 0);
      }
    }
    #pragma unroll
    for (int mi = 0; mi < 4; mi++)
      #pragma unroll
      for (int r = 0; r < 4; r++) {
        float v = fminf(msq0 - 2.f*acc[mi][0][r], msq1 - 2.f*acc[mi][1][r]);
        vmin[mi][r] = fminf(vmin[mi][r], v);
      }
    __syncthreads();
    cur ^= 1;
  }
#undef STAGE

  #pragma unroll
  for (int mi = 0; mi < 4; mi++)
    #pragma unroll
    for (int r = 0; r < 4; r++) {
      float v = vmin[mi][r];
      v = fminf(v, __shfl_xor(v, 1));
      v = fminf(v, __shfl_xor(v, 2));
      v = fminf(v, __shfl_xor(v, 4));
      v = fminf(v, __shfl_xor(v, 8));
      if (l15 == 0) red[wc][wr * 64 + mi * 16 + l4 * 4 + r] = v;
    }
  __syncthreads();
  if (t < 128) {
    float v = fminf(red[0][t], red[1][t]);
    float d2 = qsq[m0 + t] + v;
    partial[(size_t)(m0 + t) * NCHUNKS + nc] = fmaxf(d2, 0.f);
  }
}

// ============================================================================
// Fused cooperative kernel (512 blocks x 256 thr), static LDS = 65536 exactly
// ============================================================================
__global__ __launch_bounds__(256, 2) void k_fused(
    const float* __restrict__ image, const float* __restrict__ geometry,
    const float* __restrict__ bw, const float* __restrict__ bb,
    const float* __restrict__ fwp, const float* __restrict__ fb,
    const float* __restrict__ mb,
    short* __restrict__ flatb, float* __restrict__ qsq, float* __restrict__ wgt,
    short* __restrict__ mbb, float* __restrict__ msq,
    float* __restrict__ partial, float* __restrict__ out)
{
  __shared__ __align__(16) unsigned char shmem[65536];
  cg::grid_group grid = cg::this_grid();
  int t = threadIdx.x;
  int bid = blockIdx.x;

  // Phase A
  if (bid < 256) {
    conv_block_256(shmem, bid, t, image, geometry, bw, bb, fwp, fb,
                   flatb, qsq, wgt);
  } else {
    for (int ss = 0; ss < 4; ss++)
      bank_subtile_256(shmem, (bid - 256) * 4 + ss, t, mb, mbb, msq);
  }

  grid.sync();

  // Phase B: distmin (nc = bid&31, mt = bid>>5)
  distmin_block(shmem, bid & 31, bid >> 5, t, flatb, mbb, qsq, msq, partial);

  grid.sync();

  // Phase C: final
  if (bid < 8) {
    int q = bid * 256 + t;
    const float4* p = (const float4*)(partial + (size_t)q * NCHUNKS);
    float v = 3.4e38f;
    #pragma unroll
    for (int j = 0; j < 8; j++) {
      float4 x = p[j];
      v = fminf(v, fminf(fminf(x.x, x.y), fminf(x.z, x.w)));
    }
    float sp = sqrtf(v);
    out[q] = sp;
    out[NP + q] = sp * wgt[q];
  }
}

// ============================================================================
// Fallback kernels (R8 pipeline)
// ============================================================================
__global__ __launch_bounds__(256) void k_prep_fb(
    const float* __restrict__ image, const float* __restrict__ geometry,
    const float* __restrict__ bw, const float* __restrict__ bb,
    const float* __restrict__ fwp, const float* __restrict__ fb,
    const float* __restrict__ mb,
    short* __restrict__ flatb, float* __restrict__ qsq, float* __restrict__ wgt,
    short* __restrict__ mbb, float* __restrict__ msq)
{
  __shared__ __align__(16) unsigned char shmem[32768];
  int t = threadIdx.x;
  int bid = blockIdx.x;
  if (bid < 256) {
    conv_block_256(shmem, bid, t, image, geometry, bw, bb, fwp, fb,
                   flatb, qsq, wgt);
  } else {
    bank_subtile_256(shmem, bid - 256, t, mb, mbb, msq);
  }
}

__global__ __launch_bounds__(256, 2) void k_distmin_fb(
    const short* __restrict__ Aq, const short* __restrict__ Bb,
    const float* __restrict__ qsq, const float* __restrict__ msq,
    float* __restrict__ partial)
{
  __shared__ __align__(16) unsigned char shmem[65536];
  distmin_block(shmem, blockIdx.x, blockIdx.y, threadIdx.x,
                Aq, Bb, qsq, msq, partial);
}

__global__ __launch_bounds__(256) void k_final_fb(
    const float* __restrict__ partial, const float* __restrict__ wgt,
    float* __restrict__ out)
{
  int q = blockIdx.x * 256 + threadIdx.x;
  const float4* p = (const float4*)(partial + (size_t)q * NCHUNKS);
  float v = 3.4e38f;
  #pragma unroll
  for (int j = 0; j < 8; j++) {
    float4 x = p[j];
    v = fminf(v, fminf(fminf(x.x, x.y), fminf(x.z, x.w)));
  }
  float sp = sqrtf(v);
  out[q] = sp;
  out[NP + q] = sp * wgt[q];
}

extern "C" void kernel_launch(void* const* d_in, const int* in_sizes, int n_in,
                              void* d_out, int out_size, void* d_ws, size_t ws_size,
                              hipStream_t stream) {
  const float* image    = (const float*)d_in[0];
  const float* geometry = (const float*)d_in[1];
  const float* bw       = (const float*)d_in[2];
  const float* bb       = (const float*)d_in[3];
  const float* fw       = (const float*)d_in[4];
  const float* fb       = (const float*)d_in[5];
  const float* mb       = (const float*)d_in[6];
  float* out = (float*)d_out;
  char* ws = (char*)d_ws;

  float* wgt     = (float*)(ws);                  // 8 KB
  float* qsq     = (float*)(ws + 8192);           // 8 KB
  float* msq     = (float*)(ws + 16384);          // 256 KB
  float* fwp     = (float*)(ws + 278528);         // 270336 B
  short* flatb   = (short*)(ws + 548864);         // 1 MB
  float* partial = (float*)(ws + 1597440);        // 256 KB [2048][32]
  short* mbb     = (short*)(ws + 1859584);        // 32 MB  [65536][256] bf16, TILED

  // fw repack via strided d2d copy: [256][261] -> [256][264]-pitch.
  // Pad cols keep poison but multiply explicit LDS zeros (inert, finite).
  hipMemcpy2DAsync(fwp, 264 * sizeof(float), fw, 261 * sizeof(float),
                   261 * sizeof(float), 256, hipMemcpyDeviceToDevice, stream);

  // Try the fused cooperative kernel; verify co-residency first.
  int coop = 0, occ = 0;
  hipDeviceGetAttribute(&coop, hipDeviceAttributeCooperativeLaunch, 0);
  hipOccupancyMaxActiveBlocksPerMultiprocessor(&occ, (const void*)k_fused, 256, 0);

  bool launched = false;
  if (coop && occ >= 2) {
    void* args[] = {
      (void*)&image, (void*)&geometry, (void*)&bw, (void*)&bb, (void*)&fwp,
      (void*)&fb, (void*)&mb, (void*)&flatb, (void*)&qsq, (void*)&wgt,
      (void*)&mbb, (void*)&msq, (void*)&partial, (void*)&out
    };
    hipError_t err = hipLaunchCooperativeKernel((const void*)k_fused,
                                                dim3(512), dim3(256),
                                                args, 0, stream);
    launched = (err == hipSuccess);
    if (!launched) (void)hipGetLastError();   // clear sticky error
  }

  if (!launched) {
    hipLaunchKernelGGL(k_prep_fb,    dim3(1280),   dim3(256), 0, stream,
                       image, geometry, bw, bb, fwp, fb, mb,
                       flatb, qsq, wgt, mbb, msq);
    hipLaunchKernelGGL(k_distmin_fb, dim3(32, 16), dim3(256), 0, stream,
                       flatb, mbb, qsq, msq, partial);
    hipLaunchKernelGGL(k_final_fb,   dim3(8),      dim3(256), 0, stream,
                       partial, wgt, out);
  }
}